// Round 6
// baseline (407.853 us; speedup 1.0000x reference)
//
#include <hip/hip_runtime.h>
#include <hip/hip_bf16.h>
#include <math.h>

#define D_MODEL 1024
#define NH 16
#define HD 64
#define SEQ 2048
#define BATCH 2
#define NTOK (BATCH*SEQ)   // 4096

typedef short bf16x8 __attribute__((ext_vector_type(8)));
typedef short s4 __attribute__((ext_vector_type(4)));
typedef float f32x4 __attribute__((ext_vector_type(4)));
typedef unsigned short us4 __attribute__((ext_vector_type(4)));

#define MFMA(a,b,c) __builtin_amdgcn_mfma_f32_16x16x32_bf16(a,b,c,0,0,0)

union bfu { __hip_bfloat16 b; unsigned short u; };
__device__ __forceinline__ unsigned short f2b(float f){ bfu t; t.b = __float2bfloat16(f); return t.u; }
__device__ __forceinline__ float b2f(unsigned short u){ bfu t; t.u = u; return __bfloat162float(t.b); }
// fast RNE f32->bf16 bit trick: valid for all finite values (no NaN/Inf path).
__device__ __forceinline__ unsigned short f2bf(float f){
    unsigned int u = __float_as_uint(f);
    u += 0x7FFFu + ((u >> 16) & 1u);
    return (unsigned short)(u >> 16);
}

// async global->LDS, 16B per lane
__device__ __forceinline__ void g2l16(const unsigned short* g, unsigned short* l){
    __builtin_amdgcn_global_load_lds(
        (const __attribute__((address_space(1))) unsigned int*)g,
        (__attribute__((address_space(3))) unsigned int*)l, 16, 0, 0);
}

// ---- d_ws layout, in u16 units --------------------------------------------
#define OFF_X   128L
#define OFF_WQ  (OFF_X  + 4194304L)
#define OFF_BQ  (OFF_WQ + 3145728L)
#define OFF_WP  (OFF_BQ + 3072L)
#define OFF_BP  (OFF_WP + 1048576L)
#define OFF_QN  (OFF_BP + 1024L)
#define OFF_KN  (OFF_QN + 64L)
#define OFF_Q   (OFF_KN + 64L)
#define OFF_K   (OFF_Q  + 4194304L)
#define OFF_V   (OFF_K  + 4194304L)
#define OFF_A   (OFF_V  + 4194304L)
#define OFF_VT  (OFF_A  + 4194304L)

// ---------------------------------------------------------------------------
// dtype detector (f32-as-u16: ~22% exponent fields >= 0x90; bf16 N(0,1): none)
// ---------------------------------------------------------------------------
__global__ __launch_bounds__(256) void detect_kernel(
    const unsigned int* __restrict__ xraw, int* __restrict__ flag)
{
    __shared__ int cnt;
    if (threadIdx.x == 0) cnt = 0;
    __syncthreads();
    int local = 0;
    const uint4* x4 = (const uint4*)xraw;
    for (int i = threadIdx.x; i < 8192; i += 256){
        uint4 v = x4[i];
        unsigned int w[4] = {v.x, v.y, v.z, v.w};
        #pragma unroll
        for (int j=0;j<4;j++){
            local += ((w[j] & 0x7F80u) >= 0x4800u);
            local += (((w[j]>>16) & 0x7F80u) >= 0x4800u);
        }
    }
    atomicAdd(&cnt, local);
    __syncthreads();
    if (threadIdx.x == 0) *flag = (cnt > 256) ? 1 : 0;
}

// ---------------------------------------------------------------------------
// canonicalize inputs to bf16, vectorized 4-wide
// ---------------------------------------------------------------------------
__global__ __launch_bounds__(256) void convert_kernel(
    const void* __restrict__ x,  const void* __restrict__ wq,
    const void* __restrict__ bq, const void* __restrict__ wp,
    const void* __restrict__ bp, const void* __restrict__ qn,
    const void* __restrict__ kn, unsigned short* __restrict__ ws,
    const int* __restrict__ flagp)
{
    const int flag = *flagp;
    long i = (long)blockIdx.x*blockDim.x + threadIdx.x;
    const long stride = (long)gridDim.x*blockDim.x;
    const long NCH = 2098208L;
    for (; i < NCH; i += stride){
        long j = i; const void* src; long off;
        if (j < 1048576L)                  { src = x;  off = OFF_X;  }
        else if ((j -= 1048576L) < 786432L){ src = wq; off = OFF_WQ; }
        else if ((j -= 786432L)  < 768L)   { src = bq; off = OFF_BQ; }
        else if ((j -= 768L)     < 262144L){ src = wp; off = OFF_WP; }
        else if ((j -= 262144L)  < 256L)   { src = bp; off = OFF_BP; }
        else if ((j -= 256L)     < 16L)    { src = qn; off = OFF_QN; }
        else      { j -= 16L;                src = kn; off = OFF_KN; }
        us4 o;
        if (flag){
            float4 v = ((const float4*)src)[j];
            o.x = f2b(v.x); o.y = f2b(v.y); o.z = f2b(v.z); o.w = f2b(v.w);
        } else {
            o = ((const us4*)src)[j];
        }
        *(us4*)(ws + off + j*4) = o;
    }
}

// ---------------------------------------------------------------------------
// Kernel 1: qkv = x @ Wqkv^T + bqkv, fused per-head RMS norm on q,k.
// ---------------------------------------------------------------------------
__global__ __launch_bounds__(256) void qkv_kernel(
    const unsigned short* __restrict__ x,
    const unsigned short* __restrict__ Wqkv,
    const unsigned short* __restrict__ bqkv,
    const unsigned short* __restrict__ qn_w,
    const unsigned short* __restrict__ kn_w,
    unsigned short* __restrict__ qbuf,
    unsigned short* __restrict__ kbuf,
    unsigned short* __restrict__ vbuf)
{
    __shared__ __align__(16) unsigned short tA[128*32];
    __shared__ __align__(16) unsigned short tB[128*32];
    const int tid  = threadIdx.x;
    const int w    = tid >> 6, lane = tid & 63, quad = lane >> 4, c = lane & 15;
    const int m0 = blockIdx.y*128, n0 = blockIdx.x*128;
    const int am = (w>>1)*64, bn = (w&1)*64;

    f32x4 acc[4][4];
    for (int mi=0;mi<4;mi++) for (int ni=0;ni<4;ni++) acc[mi][ni] = {0.f,0.f,0.f,0.f};

    const int i0 = tid, i1 = tid + 256;
    const long ga0 = (long)(m0 + (i0>>2))*D_MODEL + (i0&3)*8;
    const long ga1 = (long)(m0 + (i1>>2))*D_MODEL + (i1&3)*8;
    const long gb0 = (long)(n0 + (i0>>2))*D_MODEL + (i0&3)*8;
    const long gb1 = (long)(n0 + (i1>>2))*D_MODEL + (i1&3)*8;

    for (int k0=0;k0<D_MODEL;k0+=32){
        g2l16(x    + ga0 + k0, tA + i0*8);
        g2l16(x    + ga1 + k0, tA + i1*8);
        g2l16(Wqkv + gb0 + k0, tB + i0*8);
        g2l16(Wqkv + gb1 + k0, tB + i1*8);
        __syncthreads();
        bf16x8 a[4], b[4];
        for (int mi=0;mi<4;mi++) a[mi] = *(const bf16x8*)(tA + (am + mi*16 + c)*32 + quad*8);
        for (int ni=0;ni<4;ni++) b[ni] = *(const bf16x8*)(tB + (bn + ni*16 + c)*32 + quad*8);
        for (int mi=0;mi<4;mi++)
            for (int ni=0;ni<4;ni++)
                acc[mi][ni] = MFMA(a[mi], b[ni], acc[mi][ni]);
        __syncthreads();
    }

    const int nw = n0 + bn, mw = m0 + am;
    const int region = nw >> 10;          // 0=q, 1=k, 2=v
    const int h      = (nw & 1023) >> 6;
    float bias[4], wn[4];
    for (int ni=0;ni<4;ni++){
        bias[ni] = b2f(bqkv[nw + ni*16 + c]);
        wn[ni]   = 1.0f;
    }
    if (region==0) for (int ni=0;ni<4;ni++) wn[ni] = b2f(qn_w[ni*16+c]);
    if (region==1) for (int ni=0;ni<4;ni++) wn[ni] = b2f(kn_w[ni*16+c]);
    unsigned short* dst = (region==0) ? qbuf : (region==1) ? kbuf : vbuf;

    for (int mi=0;mi<4;mi++){
        for (int ni=0;ni<4;ni++)
            for (int r=0;r<4;r++) acc[mi][ni][r] += bias[ni];

        float scale_r[4];
        if (region < 2){
            for (int r=0;r<4;r++){
                float ss = 0.f;
                for (int ni=0;ni<4;ni++){ float v2 = acc[mi][ni][r]; ss += v2*v2; }
                ss += __shfl_xor(ss, 1, 64);
                ss += __shfl_xor(ss, 2, 64);
                ss += __shfl_xor(ss, 4, 64);
                ss += __shfl_xor(ss, 8, 64);
                scale_r[r] = rsqrtf(ss*(1.0f/64.0f) + 1e-6f);
            }
        } else {
            for (int r=0;r<4;r++) scale_r[r] = 1.0f;
        }

        for (int r=0;r<4;r++){
            int m = mw + mi*16 + quad*4 + r;
            int bidx = m >> 11, s = m & 2047;
            long base = ((long)(bidx*NH + h)*SEQ + s)*HD;
            for (int ni=0;ni<4;ni++)
                dst[base + ni*16 + c] = f2bf(acc[mi][ni][r] * scale_r[r] * wn[ni]);
        }
    }
}

// ---------------------------------------------------------------------------
// Kernel 1.5: V^T materialization: vbuf [bh][s][d] -> vtbuf [bh][d][s].
// 64x64 tiles through LDS; coalesced read and write.
// ---------------------------------------------------------------------------
__global__ __launch_bounds__(256) void vtrans_kernel(
    const unsigned short* __restrict__ vbuf,
    unsigned short* __restrict__ vtbuf)
{
    const int tid = threadIdx.x;
    const int bh = blockIdx.y, s0 = blockIdx.x*64;
    __shared__ __align__(16) unsigned short t[64][72];

    const unsigned short* src = vbuf + (long)bh*SEQ*HD + (long)s0*HD;
    #pragma unroll
    for (int it=0; it<2; it++){
        int idx = tid + it*256;               // 512 chunks of 8
        int si = idx >> 3, d0 = (idx & 7)*8;
        *(bf16x8*)(&t[si][d0]) = *(const bf16x8*)(src + si*HD + d0);
    }
    __syncthreads();

    const int d = tid >> 2, sc = (tid & 3)*16;
    unsigned short* dst = vtbuf + ((long)bh*HD + d)*SEQ + s0 + sc;
    bf16x8 o0, o1;
    #pragma unroll
    for (int j=0;j<8;j++){ o0[j] = t[sc+j][d]; o1[j] = t[sc+8+j][d]; }
    *(bf16x8*)(dst)     = o0;
    *(bf16x8*)(dst + 8) = o1;
}

// ---------------------------------------------------------------------------
// Kernel 2: attention. Fixed-max softmax (|s|<=8 by Cauchy-Schwarz, M=12).
// S^T = K*Q^T; P wave-private LDS round-trip (NO barriers in k-loop);
// PV B-frags direct from global V^T; denominator = lane-local scalar sum.
// Block = 4 waves x 16 qrows = 64 qrows. Grid (32, 32) = 1024 blocks.
// ---------------------------------------------------------------------------
__global__ __launch_bounds__(256) void attn_kernel(
    const unsigned short* __restrict__ qbuf,
    const unsigned short* __restrict__ kbuf,
    const unsigned short* __restrict__ vtbuf,
    unsigned short* __restrict__ abuf)
{
    const int tid = threadIdx.x, w = tid>>6, lane = tid&63, quad = lane>>4, c = lane&15;
    const int bh = blockIdx.y, qt = blockIdx.x;
    const unsigned short* qb = qbuf  + (long)bh*SEQ*HD;
    const unsigned short* kb = kbuf  + (long)bh*SEQ*HD;
    const unsigned short* vt = vtbuf + (long)bh*HD*SEQ;   // [d][s]
    const int qbase = qt*64 + w*16;

    // P frag-ordered, wave-private: [key8(8)][qrow(16)][kk(8)] shorts = 2KB/wave
    __shared__ __align__(16) short P[4][1024];
    short* Pw = &P[w][0];

    // Q frags (B-operand of S^T): lane holds Q[qbase+c][ks*32+quad*8+j]
    bf16x8 aq[2];
    #pragma unroll
    for (int ks=0;ks<2;ks++)
        aq[ks] = *(const bf16x8*)(qb + (long)(qbase + c)*HD + ks*32 + quad*8);

    f32x4 o[4];
    #pragma unroll
    for (int nt=0;nt<4;nt++) o[nt] = {0.f,0.f,0.f,0.f};
    float l_loc = 0.f;

    bf16x8 kA[4][2], kB[4][2];
    auto loadK = [&](int key0, bf16x8 (*kf)[2]){
        #pragma unroll
        for (int mt=0;mt<4;mt++)
            #pragma unroll
            for (int ks=0;ks<2;ks++)
                kf[mt][ks] = *(const bf16x8*)(kb + (long)(key0 + mt*16 + c)*HD + ks*32 + quad*8);
    };
    loadK(0, kA);

    for (int kt=0; kt<SEQ/64; kt++){
        const int key0 = kt*64;

        // issue V^T frag loads early (consumed at the end of the tile)
        bf16x8 bv[2][4];
        #pragma unroll
        for (int ks=0;ks<2;ks++)
            #pragma unroll
            for (int nt=0;nt<4;nt++)
                bv[ks][nt] = *(const bf16x8*)(vt + (long)(nt*16 + c)*SEQ + key0 + ks*32 + quad*8);

        // prefetch next tile's K frags
        if (kt < SEQ/64 - 1) loadK(key0 + 64, (kt&1) ? kA : kB);
        bf16x8 (*kf)[2] = (kt&1) ? kB : kA;

        // S^T = K * Q^T : C-layout row = key (quad*4+r), col = qrow (c)
        f32x4 z[4];
        #pragma unroll
        for (int mt=0;mt<4;mt++){
            f32x4 t = {0.f,0.f,0.f,0.f};
            t = MFMA(kf[mt][0], aq[0], t);
            t = MFMA(kf[mt][1], aq[1], t);
            z[mt] = t;
        }

        // p = exp(s-12) = exp2(z*log2e/8 - 12*log2e); accumulate denominator
        #pragma unroll
        for (int mt=0;mt<4;mt++){
            const int key8 = mt*2 + (quad>>1);
            s4 pk;
            #pragma unroll
            for (int r=0;r<4;r++){
                float p = exp2f(z[mt][r]*0.18033688f - 17.312340f);
                l_loc += p;
                pk[r] = (short)f2bf(p);
            }
            *(s4*)(Pw + (key8*16 + c)*8 + (quad&1)*4) = pk;
        }

        // O += P V : A = P frag (b128), B = global V^T frag
        #pragma unroll
        for (int ks=0;ks<2;ks++){
            bf16x8 ap = *(const bf16x8*)(Pw + ((ks*4+quad)*16 + c)*8);
            #pragma unroll
            for (int nt=0;nt<4;nt++)
                o[nt] = MFMA(ap, bv[ks][nt], o[nt]);
        }
    }

    // denominator: lane holds partial for qrow=c; reduce across quads
    l_loc += __shfl_xor(l_loc, 16, 64);
    l_loc += __shfl_xor(l_loc, 32, 64);

    const int b = bh >> 4, h = bh & 15;
    #pragma unroll
    for (int r=0;r<4;r++){
        float l = __shfl(l_loc, quad*4 + r, 64);   // l for qrow quad*4+r
        float inv = 1.0f / l;
        int s = qbase + quad*4 + r;
        long base = ((long)(b*SEQ + s)*NH + h)*HD;
        #pragma unroll
        for (int nt=0;nt<4;nt++)
            abuf[base + nt*16 + c] = f2bf(o[nt][r]*inv);
    }
}

// ---------------------------------------------------------------------------
// Kernel 3: out = attn @ Wproj^T + bproj, output dtype by flag
// ---------------------------------------------------------------------------
__global__ __launch_bounds__(256) void proj_kernel(
    const unsigned short* __restrict__ abuf,
    const unsigned short* __restrict__ Wp,
    const unsigned short* __restrict__ bp,
    void* __restrict__ outv,
    const int* __restrict__ flagp)
{
    __shared__ __align__(16) unsigned short tA[128*32];
    __shared__ __align__(16) unsigned short tB[128*32];
    const int tid  = threadIdx.x;
    const int w    = tid >> 6, lane = tid & 63, quad = lane >> 4, c = lane & 15;
    const int m0 = blockIdx.y*128, n0 = blockIdx.x*128;
    const int am = (w>>1)*64, bn = (w&1)*64;
    const int flag = *flagp;

    f32x4 acc[4][4];
    for (int mi=0;mi<4;mi++) for (int ni=0;ni<4;ni++) acc[mi][ni] = {0.f,0.f,0.f,0.f};

    const int i0 = tid, i1 = tid + 256;
    const long ga0 = (long)(m0 + (i0>>2))*D_MODEL + (i0&3)*8;
    const long ga1 = (long)(m0 + (i1>>2))*D_MODEL + (i1&3)*8;
    const long gb0 = (long)(n0 + (i0>>2))*D_MODEL + (i0&3)*8;
    const long gb1 = (long)(n0 + (i1>>2))*D_MODEL + (i1&3)*8;

    for (int k0=0;k0<D_MODEL;k0+=32){
        g2l16(abuf + ga0 + k0, tA + i0*8);
        g2l16(abuf + ga1 + k0, tA + i1*8);
        g2l16(Wp   + gb0 + k0, tB + i0*8);
        g2l16(Wp   + gb1 + k0, tB + i1*8);
        __syncthreads();
        bf16x8 a[4], b[4];
        for (int mi=0;mi<4;mi++) a[mi] = *(const bf16x8*)(tA + (am + mi*16 + c)*32 + quad*8);
        for (int ni=0;ni<4;ni++) b[ni] = *(const bf16x8*)(tB + (bn + ni*16 + c)*32 + quad*8);
        for (int mi=0;mi<4;mi++)
            for (int ni=0;ni<4;ni++)
                acc[mi][ni] = MFMA(a[mi], b[ni], acc[mi][ni]);
        __syncthreads();
    }

    float bias[4];
    for (int ni=0;ni<4;ni++) bias[ni] = b2f(bp[n0 + bn + ni*16 + c]);

    for (int mi=0;mi<4;mi++)
        for (int r=0;r<4;r++){
            long m = m0 + am + mi*16 + quad*4 + r;
            for (int ni=0;ni<4;ni++){
                float val = acc[mi][ni][r] + bias[ni];
                long idx = m*D_MODEL + n0 + bn + ni*16 + c;
                if (flag) ((float*)outv)[idx] = val;
                else      ((unsigned short*)outv)[idx] = f2bf(val);
            }
        }
}

extern "C" void kernel_launch(void* const* d_in, const int* in_sizes, int n_in,
                              void* d_out, int out_size, void* d_ws, size_t ws_size,
                              hipStream_t stream)
{
    unsigned short* ws = (unsigned short*)d_ws;
    int* flag = (int*)d_ws;

    hipLaunchKernelGGL(detect_kernel, dim3(1), dim3(256), 0, stream,
                       (const unsigned int*)d_in[0], flag);
    hipLaunchKernelGGL(convert_kernel, dim3(2048), dim3(256), 0, stream,
                       d_in[0], d_in[1], d_in[2], d_in[3], d_in[4], d_in[5], d_in[6],
                       ws, flag);
    hipLaunchKernelGGL(qkv_kernel,  dim3(24,32), dim3(256), 0, stream,
                       ws+OFF_X, ws+OFF_WQ, ws+OFF_BQ, ws+OFF_QN, ws+OFF_KN,
                       ws+OFF_Q, ws+OFF_K, ws+OFF_V);
    hipLaunchKernelGGL(vtrans_kernel, dim3(32,32), dim3(256), 0, stream,
                       ws+OFF_V, ws+OFF_VT);
    hipLaunchKernelGGL(attn_kernel, dim3(32,32), dim3(256), 0, stream,
                       ws+OFF_Q, ws+OFF_K, ws+OFF_VT, ws+OFF_A);
    hipLaunchKernelGGL(proj_kernel, dim3(8,32),  dim3(256), 0, stream,
                       ws+OFF_A, ws+OFF_WP, ws+OFF_BP, d_out, flag);
}

// Round 7
// 276.917 us; speedup vs baseline: 1.4728x; 1.4728x over previous
//
#include <hip/hip_runtime.h>
#include <hip/hip_bf16.h>
#include <math.h>

#define D_MODEL 1024
#define NH 16
#define HD 64
#define SEQ 2048
#define BATCH 2
#define NTOK (BATCH*SEQ)   // 4096

typedef short bf16x8 __attribute__((ext_vector_type(8)));
typedef short s4 __attribute__((ext_vector_type(4)));
typedef float f32x4 __attribute__((ext_vector_type(4)));
typedef unsigned short us4 __attribute__((ext_vector_type(4)));

#define MFMA(a,b,c) __builtin_amdgcn_mfma_f32_16x16x32_bf16(a,b,c,0,0,0)

union bfu { __hip_bfloat16 b; unsigned short u; };
__device__ __forceinline__ unsigned short f2b(float f){ bfu t; t.b = __float2bfloat16(f); return t.u; }
__device__ __forceinline__ float b2f(unsigned short u){ bfu t; t.u = u; return __bfloat162float(t.b); }
// fast RNE f32->bf16 bit trick (finite values only)
__device__ __forceinline__ unsigned short f2bf(float f){
    unsigned int u = __float_as_uint(f);
    u += 0x7FFFu + ((u >> 16) & 1u);
    return (unsigned short)(u >> 16);
}

// async global->LDS, 16B per lane
__device__ __forceinline__ void g2l16(const unsigned short* g, unsigned short* l){
    __builtin_amdgcn_global_load_lds(
        (const __attribute__((address_space(1))) unsigned int*)g,
        (__attribute__((address_space(3))) unsigned int*)l, 16, 0, 0);
}

// ---- d_ws layout, in u16 units --------------------------------------------
// ws[0..1]: int exponent-counter (dtype detect)
#define OFF_X   128L
#define OFF_WQ  (OFF_X  + 4194304L)
#define OFF_BQ  (OFF_WQ + 3145728L)
#define OFF_WP  (OFF_BQ + 3072L)
#define OFF_BP  (OFF_WP + 1048576L)
#define OFF_QN  (OFF_BP + 1024L)
#define OFF_KN  (OFF_QN + 64L)
#define OFF_Q   (OFF_KN + 64L)
#define OFF_K   (OFF_Q  + 4194304L)
#define OFF_V   (OFF_K  + 4194304L)
#define OFF_A   (OFF_V  + 4194304L)
#define OFF_OP  (OFF_A  + 4194304L)      // f32 O-partial (4194304 f32) + l (65536 f32)

// ---------------------------------------------------------------------------
// dtype detector: 16 blocks, one uint4 per thread over first 65536 u16 of x.
// f32-as-u16: ~22% of exponent fields >= 0x90; bf16 N(0,1): none.
// ---------------------------------------------------------------------------
__global__ __launch_bounds__(256) void detect_kernel(
    const unsigned int* __restrict__ xraw, int* __restrict__ cnt)
{
    int i = blockIdx.x*256 + threadIdx.x;
    uint4 v = ((const uint4*)xraw)[i];
    unsigned int w[4] = {v.x, v.y, v.z, v.w};
    int local = 0;
    #pragma unroll
    for (int j=0;j<4;j++){
        local += ((w[j] & 0x7F80u) >= 0x4800u);
        local += (((w[j]>>16) & 0x7F80u) >= 0x4800u);
    }
    if (local) atomicAdd(cnt, local);
}

// ---------------------------------------------------------------------------
// canonicalize inputs to bf16, vectorized 4-wide
// ---------------------------------------------------------------------------
__global__ __launch_bounds__(256) void convert_kernel(
    const void* __restrict__ x,  const void* __restrict__ wq,
    const void* __restrict__ bq, const void* __restrict__ wp,
    const void* __restrict__ bp, const void* __restrict__ qn,
    const void* __restrict__ kn, unsigned short* __restrict__ ws,
    const int* __restrict__ cntp)
{
    const int flag = (*cntp > 256);
    long i = (long)blockIdx.x*blockDim.x + threadIdx.x;
    const long stride = (long)gridDim.x*blockDim.x;
    const long NCH = 2098208L;
    for (; i < NCH; i += stride){
        long j = i; const void* src; long off;
        if (j < 1048576L)                  { src = x;  off = OFF_X;  }
        else if ((j -= 1048576L) < 786432L){ src = wq; off = OFF_WQ; }
        else if ((j -= 786432L)  < 768L)   { src = bq; off = OFF_BQ; }
        else if ((j -= 768L)     < 262144L){ src = wp; off = OFF_WP; }
        else if ((j -= 262144L)  < 256L)   { src = bp; off = OFF_BP; }
        else if ((j -= 256L)     < 16L)    { src = qn; off = OFF_QN; }
        else      { j -= 16L;                src = kn; off = OFF_KN; }
        us4 o;
        if (flag){
            float4 v = ((const float4*)src)[j];
            o.x = f2b(v.x); o.y = f2b(v.y); o.z = f2b(v.z); o.w = f2b(v.w);
        } else {
            o = ((const us4*)src)[j];
        }
        *(us4*)(ws + off + j*4) = o;
    }
}

// ---------------------------------------------------------------------------
// Kernel 1: qkv = x @ Wqkv^T + bqkv, fused per-head RMS norm on q,k.
// ---------------------------------------------------------------------------
__global__ __launch_bounds__(256) void qkv_kernel(
    const unsigned short* __restrict__ x,
    const unsigned short* __restrict__ Wqkv,
    const unsigned short* __restrict__ bqkv,
    const unsigned short* __restrict__ qn_w,
    const unsigned short* __restrict__ kn_w,
    unsigned short* __restrict__ qbuf,
    unsigned short* __restrict__ kbuf,
    unsigned short* __restrict__ vbuf)
{
    __shared__ __align__(16) unsigned short tA[128*32];
    __shared__ __align__(16) unsigned short tB[128*32];
    const int tid  = threadIdx.x;
    const int w    = tid >> 6, lane = tid & 63, quad = lane >> 4, c = lane & 15;
    const int m0 = blockIdx.y*128, n0 = blockIdx.x*128;
    const int am = (w>>1)*64, bn = (w&1)*64;

    f32x4 acc[4][4];
    for (int mi=0;mi<4;mi++) for (int ni=0;ni<4;ni++) acc[mi][ni] = {0.f,0.f,0.f,0.f};

    const int i0 = tid, i1 = tid + 256;
    const long ga0 = (long)(m0 + (i0>>2))*D_MODEL + (i0&3)*8;
    const long ga1 = (long)(m0 + (i1>>2))*D_MODEL + (i1&3)*8;
    const long gb0 = (long)(n0 + (i0>>2))*D_MODEL + (i0&3)*8;
    const long gb1 = (long)(n0 + (i1>>2))*D_MODEL + (i1&3)*8;

    for (int k0=0;k0<D_MODEL;k0+=32){
        g2l16(x    + ga0 + k0, tA + i0*8);
        g2l16(x    + ga1 + k0, tA + i1*8);
        g2l16(Wqkv + gb0 + k0, tB + i0*8);
        g2l16(Wqkv + gb1 + k0, tB + i1*8);
        __syncthreads();
        bf16x8 a[4], b[4];
        for (int mi=0;mi<4;mi++) a[mi] = *(const bf16x8*)(tA + (am + mi*16 + c)*32 + quad*8);
        for (int ni=0;ni<4;ni++) b[ni] = *(const bf16x8*)(tB + (bn + ni*16 + c)*32 + quad*8);
        for (int mi=0;mi<4;mi++)
            for (int ni=0;ni<4;ni++)
                acc[mi][ni] = MFMA(a[mi], b[ni], acc[mi][ni]);
        __syncthreads();
    }

    const int nw = n0 + bn, mw = m0 + am;
    const int region = nw >> 10;          // 0=q, 1=k, 2=v
    const int h      = (nw & 1023) >> 6;
    float bias[4], wn[4];
    for (int ni=0;ni<4;ni++){
        bias[ni] = b2f(bqkv[nw + ni*16 + c]);
        wn[ni]   = 1.0f;
    }
    if (region==0) for (int ni=0;ni<4;ni++) wn[ni] = b2f(qn_w[ni*16+c]);
    if (region==1) for (int ni=0;ni<4;ni++) wn[ni] = b2f(kn_w[ni*16+c]);
    unsigned short* dst = (region==0) ? qbuf : (region==1) ? kbuf : vbuf;

    for (int mi=0;mi<4;mi++){
        for (int ni=0;ni<4;ni++)
            for (int r=0;r<4;r++) acc[mi][ni][r] += bias[ni];

        float scale_r[4];
        if (region < 2){
            for (int r=0;r<4;r++){
                float ss = 0.f;
                for (int ni=0;ni<4;ni++){ float v2 = acc[mi][ni][r]; ss += v2*v2; }
                ss += __shfl_xor(ss, 1, 64);
                ss += __shfl_xor(ss, 2, 64);
                ss += __shfl_xor(ss, 4, 64);
                ss += __shfl_xor(ss, 8, 64);
                scale_r[r] = rsqrtf(ss*(1.0f/64.0f) + 1e-6f);
            }
        } else {
            for (int r=0;r<4;r++) scale_r[r] = 1.0f;
        }

        for (int r=0;r<4;r++){
            int m = mw + mi*16 + quad*4 + r;
            int bidx = m >> 11, s = m & 2047;
            long base = ((long)(bidx*NH + h)*SEQ + s)*HD;
            for (int ni=0;ni<4;ni++)
                dst[base + ni*16 + c] = f2bf(acc[mi][ni][r] * scale_r[r] * wn[ni]);
        }
    }
}

// ---------------------------------------------------------------------------
// Kernel 2: attention, R5 structure + split-K (blockIdx.z halves key range).
// Fixed-max softmax (|s|<=8 by Cauchy-Schwarz, M=12) => partials are exactly
// additive: O = O0+O1, l = l0+l1 (ones-column of V gives l in AGPRs).
// S^T = K*Q^T swap: P stores b64, reads b128. V^T register-transpose staged,
// double-buffered LDS, one barrier/tile. Epilogue: f32 atomicAdd partials.
// Block = 4 waves x 32 qrows = 128 qrows. Grid (16, 32, 2) = 1024 blocks.
// ---------------------------------------------------------------------------
__global__ __launch_bounds__(256) void attn_kernel(
    const unsigned short* __restrict__ qbuf,
    const unsigned short* __restrict__ kbuf,
    const unsigned short* __restrict__ vbuf,
    float* __restrict__ opart,
    float* __restrict__ lpart)
{
    const int tid = threadIdx.x, w = tid>>6, lane = tid&63, quad = lane>>4, c = lane&15;
    const int bh = blockIdx.y, qt = blockIdx.x, z = blockIdx.z;
    const unsigned short* qb = qbuf + (long)bh*SEQ*HD;
    const unsigned short* kb = kbuf + (long)bh*SEQ*HD;
    const unsigned short* vb = vbuf + (long)bh*SEQ*HD;
    const int qbase = qt*128 + w*32;
    const int zbase = z*1024;

    __shared__ __align__(16) short VT[2][80][72];
    __shared__ __align__(16) short P[4][2048];
    short* Pw = &P[w][0];

    // ones-rows (dims 64..79) of both VT buffers
    for (int i = tid; i < 2*16*72; i += 256){
        int bi = i / 1152, rem = i - bi*1152;
        VT[bi][64 + rem/72][rem%72] = 0;
    }
    __syncthreads();
    if (tid < 128) VT[tid>>6][64][tid&63] = 0x3F80;   // bf16 1.0

    bf16x8 aq[2][2];
    for (int mi=0;mi<2;mi++)
        for (int ks=0;ks<2;ks++)
            aq[mi][ks] = *(const bf16x8*)(qb + (long)(qbase + mi*16 + c)*HD + ks*32 + quad*8);

    f32x4 o[2][5];
    for (int mi=0;mi<2;mi++) for (int nt=0;nt<5;nt++) o[mi][nt] = {0.f,0.f,0.f,0.f};

    const int d0 = (tid & 31)*2;
    const int kg = tid >> 5;

    unsigned int vA[8], vB[8];
    bf16x8 kA[4][2], kB[4][2];

    auto stageV = [&](int key0, unsigned int* vr){
        #pragma unroll
        for (int j=0;j<8;j++)
            vr[j] = *(const unsigned int*)(vb + (long)(key0 + kg*8 + j)*HD + d0);
    };
    auto loadK = [&](int key0, bf16x8 (*kf)[2]){
        #pragma unroll
        for (int mt=0;mt<4;mt++)
            #pragma unroll
            for (int ks=0;ks<2;ks++)
                kf[mt][ks] = *(const bf16x8*)(kb + (long)(key0 + mt*16 + c)*HD + ks*32 + quad*8);
    };
    auto writeV = [&](unsigned int* vr, short (*vt)[72]){
        bf16x8 lo, hi;
        #pragma unroll
        for (int j=0;j<8;j++){
            lo[j] = (short)(vr[j] & 0xffffu);
            hi[j] = (short)(vr[j] >> 16);
        }
        *(bf16x8*)(&vt[d0][kg*8])   = lo;
        *(bf16x8*)(&vt[d0+1][kg*8]) = hi;
    };
    auto compute = [&](short (*vt)[72], bf16x8 (*kf)[2]){
        f32x4 z4[4][2];
        #pragma unroll
        for (int mt=0;mt<4;mt++)
            #pragma unroll
            for (int mi=0;mi<2;mi++){
                f32x4 t = {0.f,0.f,0.f,0.f};
                t = MFMA(kf[mt][0], aq[mi][0], t);
                t = MFMA(kf[mt][1], aq[mi][1], t);
                z4[mt][mi] = t;
            }
        #pragma unroll
        for (int mt=0;mt<4;mt++){
            const int key8 = mt*2 + (quad>>1);
            #pragma unroll
            for (int mi=0;mi<2;mi++){
                s4 pk;
                #pragma unroll
                for (int r=0;r<4;r++)
                    pk[r] = (short)f2bf(exp2f(z4[mt][mi][r]*0.18033688f - 17.312340f));
                *(s4*)(Pw + (key8*32 + mi*16 + c)*8 + (quad&1)*4) = pk;
            }
        }
        #pragma unroll
        for (int ks=0;ks<2;ks++){
            bf16x8 bv[5];
            #pragma unroll
            for (int nt=0;nt<5;nt++)
                bv[nt] = *(const bf16x8*)(&vt[nt*16 + c][ks*32 + quad*8]);
            #pragma unroll
            for (int mi=0;mi<2;mi++){
                bf16x8 ap = *(const bf16x8*)(Pw + ((ks*4+quad)*32 + mi*16 + c)*8);
                #pragma unroll
                for (int nt=0;nt<5;nt++)
                    o[mi][nt] = MFMA(ap, bv[nt], o[mi][nt]);
            }
        }
    };

    stageV(zbase, vA); loadK(zbase, kA);
    for (int tt=0; tt<8; tt++){
        const int k1 = zbase + (tt*2 + 1)*64;
        writeV(vA, VT[0]);
        __syncthreads();
        stageV(k1, vB); loadK(k1, kB);
        compute(VT[0], kA);
        writeV(vB, VT[1]);
        __syncthreads();
        if (tt < 7){ stageV(k1 + 64, vA); loadK(k1 + 64, kA); }
        compute(VT[1], kB);
    }

    // epilogue: atomicAdd f32 partials (additive across z — fixed-max softmax)
    const int b = bh >> 4, h = bh & 15;
    for (int mi=0;mi<2;mi++)
        for (int r=0;r<4;r++){
            int s = qbase + mi*16 + quad*4 + r;
            long obase = ((long)(b*SEQ + s)*NH + h)*HD;
            for (int nt=0;nt<4;nt++)
                atomicAdd(&opart[obase + nt*16 + c], o[mi][nt][r]);
            if (c == 0)
                atomicAdd(&lpart[(long)bh*SEQ + s], o[mi][4][r]);
        }
}

// ---------------------------------------------------------------------------
// Kernel 2.5: combine = O/l, cast bf16. 4 f32 per thread.
// ---------------------------------------------------------------------------
__global__ __launch_bounds__(256) void combine_kernel(
    const float* __restrict__ opart, const float* __restrict__ lpart,
    unsigned short* __restrict__ abuf)
{
    long i = (long)blockIdx.x*256 + threadIdx.x;   // chunk of 4 f32
    long j = i*4;
    int s = (int)((j>>10)&2047), h = (int)((j>>6)&15), b = (int)(j>>21);
    float inv = 1.0f / lpart[((long)(b*NH + h))*SEQ + s];
    float4 v = ((const float4*)opart)[i];
    us4 o;
    o.x = f2bf(v.x*inv); o.y = f2bf(v.y*inv);
    o.z = f2bf(v.z*inv); o.w = f2bf(v.w*inv);
    ((us4*)abuf)[i] = o;
}

// ---------------------------------------------------------------------------
// Kernel 3: out = attn @ Wproj^T + bproj, output dtype by flag
// ---------------------------------------------------------------------------
__global__ __launch_bounds__(256) void proj_kernel(
    const unsigned short* __restrict__ abuf,
    const unsigned short* __restrict__ Wp,
    const unsigned short* __restrict__ bp,
    void* __restrict__ outv,
    const int* __restrict__ cntp)
{
    __shared__ __align__(16) unsigned short tA[128*32];
    __shared__ __align__(16) unsigned short tB[128*32];
    const int tid  = threadIdx.x;
    const int w    = tid >> 6, lane = tid & 63, quad = lane >> 4, c = lane & 15;
    const int m0 = blockIdx.y*128, n0 = blockIdx.x*128;
    const int am = (w>>1)*64, bn = (w&1)*64;
    const int flag = (*cntp > 256);

    f32x4 acc[4][4];
    for (int mi=0;mi<4;mi++) for (int ni=0;ni<4;ni++) acc[mi][ni] = {0.f,0.f,0.f,0.f};

    const int i0 = tid, i1 = tid + 256;
    const long ga0 = (long)(m0 + (i0>>2))*D_MODEL + (i0&3)*8;
    const long ga1 = (long)(m0 + (i1>>2))*D_MODEL + (i1&3)*8;
    const long gb0 = (long)(n0 + (i0>>2))*D_MODEL + (i0&3)*8;
    const long gb1 = (long)(n0 + (i1>>2))*D_MODEL + (i1&3)*8;

    for (int k0=0;k0<D_MODEL;k0+=32){
        g2l16(abuf + ga0 + k0, tA + i0*8);
        g2l16(abuf + ga1 + k0, tA + i1*8);
        g2l16(Wp   + gb0 + k0, tB + i0*8);
        g2l16(Wp   + gb1 + k0, tB + i1*8);
        __syncthreads();
        bf16x8 a[4], b[4];
        for (int mi=0;mi<4;mi++) a[mi] = *(const bf16x8*)(tA + (am + mi*16 + c)*32 + quad*8);
        for (int ni=0;ni<4;ni++) b[ni] = *(const bf16x8*)(tB + (bn + ni*16 + c)*32 + quad*8);
        for (int mi=0;mi<4;mi++)
            for (int ni=0;ni<4;ni++)
                acc[mi][ni] = MFMA(a[mi], b[ni], acc[mi][ni]);
        __syncthreads();
    }

    float bias[4];
    for (int ni=0;ni<4;ni++) bias[ni] = b2f(bp[n0 + bn + ni*16 + c]);

    for (int mi=0;mi<4;mi++)
        for (int r=0;r<4;r++){
            long m = m0 + am + mi*16 + quad*4 + r;
            for (int ni=0;ni<4;ni++){
                float val = acc[mi][ni][r] + bias[ni];
                long idx = m*D_MODEL + n0 + bn + ni*16 + c;
                if (flag) ((float*)outv)[idx] = val;
                else      ((unsigned short*)outv)[idx] = f2bf(val);
            }
        }
}

extern "C" void kernel_launch(void* const* d_in, const int* in_sizes, int n_in,
                              void* d_out, int out_size, void* d_ws, size_t ws_size,
                              hipStream_t stream)
{
    unsigned short* ws = (unsigned short*)d_ws;
    int* cnt = (int*)d_ws;
    float* opart = (float*)(ws + OFF_OP);
    float* lpart = opart + 4194304L;

    hipMemsetAsync(cnt, 0, 4, stream);
    hipMemsetAsync(opart, 0, (4194304L + 65536L)*4, stream);

    hipLaunchKernelGGL(detect_kernel, dim3(16), dim3(256), 0, stream,
                       (const unsigned int*)d_in[0], cnt);
    hipLaunchKernelGGL(convert_kernel, dim3(2048), dim3(256), 0, stream,
                       d_in[0], d_in[1], d_in[2], d_in[3], d_in[4], d_in[5], d_in[6],
                       ws, cnt);
    hipLaunchKernelGGL(qkv_kernel,  dim3(24,32), dim3(256), 0, stream,
                       ws+OFF_X, ws+OFF_WQ, ws+OFF_BQ, ws+OFF_QN, ws+OFF_KN,
                       ws+OFF_Q, ws+OFF_K, ws+OFF_V);
    hipLaunchKernelGGL(attn_kernel, dim3(16,32,2), dim3(256), 0, stream,
                       ws+OFF_Q, ws+OFF_K, ws+OFF_V, opart, lpart);
    hipLaunchKernelGGL(combine_kernel, dim3(4096), dim3(256), 0, stream,
                       opart, lpart, ws+OFF_A);
    hipLaunchKernelGGL(proj_kernel, dim3(8,32),  dim3(256), 0, stream,
                       ws+OFF_A, ws+OFF_WP, ws+OFF_BP, d_out, cnt);
}